// Round 15
// baseline (86.448 us; speedup 1.0000x reference)
//
#include <hip/hip_runtime.h>
#include <hip/hip_bf16.h>

typedef __attribute__((ext_vector_type(8))) unsigned short ushort8;
typedef __attribute__((ext_vector_type(8))) __bf16 bf16x8;
typedef __attribute__((ext_vector_type(4))) float f32x4;
typedef __attribute__((ext_vector_type(4))) unsigned short ushort4v;

__device__ __forceinline__ float lrelu_f(float v){ return v > 0.f ? v : 0.1f*v; }

__device__ __forceinline__ unsigned short f2bf(float v){
  unsigned u = __float_as_uint(v);
  unsigned r = (u + 0x7fffu + ((u>>16)&1u)) >> 16;
  return (unsigned short)r;
}
__device__ __forceinline__ float bf2f(unsigned short u){
  return __uint_as_float(((unsigned)u)<<16);
}

__device__ __forceinline__ void gload16(const void* g, void* l){
  __builtin_amdgcn_global_load_lds(
    (const __attribute__((address_space(1))) unsigned int*)g,
    (__attribute__((address_space(3))) unsigned int*)l, 16, 0, 0);
}

// load 8 elements as bf16x8-compatible ushort8, from bf16 or f32 source
__device__ __forceinline__ ushort8 ld8(const unsigned short* p){
  return *(const ushort8*)p;
}
__device__ __forceinline__ ushort8 ld8(const float* p){
  const float4 a = *(const float4*)p;
  const float4 b = *(const float4*)(p+4);
  ushort8 o;
  o[0]=f2bf(a.x); o[1]=f2bf(a.y); o[2]=f2bf(a.z); o[3]=f2bf(a.w);
  o[4]=f2bf(b.x); o[5]=f2bf(b.y); o[6]=f2bf(b.z); o[7]=f2bf(b.w);
  return o;
}

// ============ light pack: DEGT transpose-pack + conv-weight reorder ==========
__global__ __launch_bounds__(256) void k_pack_lite(
  const float* __restrict__ deg, const float* __restrict__ conv1_w,
  const float* __restrict__ conv2_w,
  unsigned short* __restrict__ DEGT,
  unsigned short* __restrict__ WB1, unsigned short* __restrict__ WB2){
  int i = blockIdx.x*256 + threadIdx.x;
  if (i < 65536){                      // DEGT: bf16 transpose of deg
    const int j = i*4; const int p = j>>9, c = j&511;
    ushort4v o;
    o.x = f2bf(deg[(size_t)(c+0)*512 + p]);
    o.y = f2bf(deg[(size_t)(c+1)*512 + p]);
    o.z = f2bf(deg[(size_t)(c+2)*512 + p]);
    o.w = f2bf(deg[(size_t)(c+3)*512 + p]);
    *(ushort4v*)(DEGT + (size_t)j) = o;
    return;
  } i -= 65536;
  const float* src; unsigned short* dst;
  if (i < 589824){ src = conv1_w; dst = WB1; }
  else { i -= 589824; if (i >= 589824) return; src = conv2_w; dst = WB2; }
  const int o_ = i/1152; const int r4 = (i - o_*1152)*4;
  const int t = r4>>9; const int ci = r4&511;
  const float* s = src + (size_t)o_*4608;
  ushort4v o;
  o.x = f2bf(s[(ci+0)*9 + t]); o.y = f2bf(s[(ci+1)*9 + t]);
  o.z = f2bf(s[(ci+2)*9 + t]); o.w = f2bf(s[(ci+3)*9 + t]);
  *(ushort4v*)(dst + (size_t)o_*4608 + r4) = o;
}

// ==== 32x32 GEMM core: 4 waves = 4 quadrants, BK=64, dbuf single-barrier ====
// Mixed source types (f32 converts inline). lA/lB: [2][2048] ushorts.
template<typename TA, typename TB>
__device__ __forceinline__ void gemm32(
    const TA* __restrict__ A, const TB* __restrict__ Bt,
    int m0, int n0, int K, int tid,
    unsigned short* lA, unsigned short* lB, f32x4& acc){
  const int wid = tid>>6, lane = tid&63;
  const int half = tid>>7, st_ = tid&127;       // wave-uniform half
  const int srow = st_>>2, skb = st_&3;
  const TA* gSa = A  + (size_t)(m0+srow)*K;
  const TB* gSb = Bt + (size_t)(n0+srow)*K;
  unsigned short* lS = half ? lB : lA;
  const int soff0 = srow*64 + 8*(skb ^ (srow&7));
  const int soff1 = srow*64 + 8*((skb+4) ^ (srow&7));

  const int wr = (wid>>1)*16, wc = (wid&1)*16;
  const int l15 = lane&15, lkb = lane>>4;
  int aoff[2], boff[2];
  #pragma unroll
  for (int h=0;h<2;h++){
    const int Ra = wr + l15;
    aoff[h] = Ra*64 + 8*((lkb+4*h) ^ (Ra&7));
    const int Rb = wc + l15;
    boff[h] = Rb*64 + 8*((lkb+4*h) ^ (Rb&7));
  }

  const int nst = K>>6;
  ushort8 r0, r1;
  if (half==0){ r0 = ld8(gSa + skb*8); r1 = ld8(gSa + (skb+4)*8); }
  else        { r0 = ld8(gSb + skb*8); r1 = ld8(gSb + (skb+4)*8); }
  *(ushort8*)(lS + soff0) = r0;
  *(ushort8*)(lS + soff1) = r1;
  if (nst > 1){
    if (half==0){ r0 = ld8(gSa + 64 + skb*8); r1 = ld8(gSa + 64 + (skb+4)*8); }
    else        { r0 = ld8(gSb + 64 + skb*8); r1 = ld8(gSb + 64 + (skb+4)*8); }
  }
  __syncthreads();
  for (int st=0; st<nst; ++st){
    const int cur = (st&1)*2048;
    bf16x8 af[2], bf[2];
    #pragma unroll
    for (int h=0;h<2;h++){
      af[h] = *(const bf16x8*)(lA + cur + aoff[h]);
      bf[h] = *(const bf16x8*)(lB + cur + boff[h]);
    }
    if (st+1 < nst){
      const int nxt = ((st+1)&1)*2048;
      *(ushort8*)(lS + nxt + soff0) = r0;
      *(ushort8*)(lS + nxt + soff1) = r1;
      if (st+2 < nst){
        if (half==0){ r0 = ld8(gSa + (size_t)(st+2)*64 + skb*8);
                      r1 = ld8(gSa + (size_t)(st+2)*64 + (skb+4)*8); }
        else        { r0 = ld8(gSb + (size_t)(st+2)*64 + skb*8);
                      r1 = ld8(gSb + (size_t)(st+2)*64 + (skb+4)*8); }
      }
    }
    #pragma unroll
    for (int h=0;h<2;h++)
      acc = __builtin_amdgcn_mfma_f32_16x16x32_bf16(af[h], bf[h], acc, 0,0,0);
    __syncthreads();
  }
}

// ======= 64x64 MFMA GEMM core, mixed types, dbuf single-barrier ========
template<typename TA, typename TB>
__device__ __forceinline__ void gemm64(
    const TA* __restrict__ A, const TB* __restrict__ Bt,
    int m0, int n0, int K, int tid,
    unsigned short* lA, unsigned short* lB, f32x4 acc[2][2]){
  const int wid = tid>>6, lane = tid&63;
  const int srow = tid>>2, skb = tid&3;
  const TA* gA = A  + (size_t)(m0+srow)*K + skb*8;
  const TB* gB = Bt + (size_t)(n0+srow)*K + skb*8;
  const int soff = srow*32 + 8*(skb ^ (srow&3));
  const int wr = (wid>>1)*32, wc = (wid&1)*32;
  const int l15 = lane&15, lkb = lane>>4;
  int aoff[2], boff[2];
  #pragma unroll
  for (int s=0;s<2;s++){
    const int Ra = wr + s*16 + l15;
    aoff[s] = Ra*32 + 8*(lkb ^ (Ra&3));
    const int Rb = wc + s*16 + l15;
    boff[s] = Rb*32 + 8*(lkb ^ (Rb&3));
  }
  const int nst = K>>5;
  ushort8 ra = ld8(gA);
  ushort8 rb = ld8(gB);
  *(ushort8*)(lA + soff) = ra;
  *(ushort8*)(lB + soff) = rb;
  if (nst > 1){ ra = ld8(gA+32); rb = ld8(gB+32); }
  __syncthreads();
  for (int st=0; st<nst; ++st){
    const int cur = (st&1)*2048;
    bf16x8 af[2], bfr[2];
    #pragma unroll
    for (int s=0;s<2;s++){
      af[s]  = *(const bf16x8*)(lA + cur + aoff[s]);
      bfr[s] = *(const bf16x8*)(lB + cur + boff[s]);
    }
    if (st+1 < nst){
      const int nxt = ((st+1)&1)*2048;
      *(ushort8*)(lA + nxt + soff) = ra;
      *(ushort8*)(lB + nxt + soff) = rb;
      if (st+2 < nst){
        ra = ld8(gA + (size_t)(st+2)*32);
        rb = ld8(gB + (size_t)(st+2)*32);
      }
    }
    #pragma unroll
    for (int mi=0;mi<2;mi++)
      #pragma unroll
      for (int ni=0;ni<2;ni++)
        acc[mi][ni] = __builtin_amdgcn_mfma_f32_16x16x32_bf16(af[mi], bfr[ni], acc[mi][ni], 0,0,0);
    __syncthreads();
  }
}

// ==== pre-phase: z=0,1 kern partial (TMP tile + in-register kw2 contraction)
//                z=2,3 HID{1,2}=lrelu(DEGT@ca_w1^T) bf16 [512][64]
__global__ __launch_bounds__(256) void k_pre(
    const float* __restrict__ deg, const unsigned short* __restrict__ DEGT,
    const float* __restrict__ k1_w1, const float* __restrict__ k2_w1,
    const float* __restrict__ ca1_w1, const float* __restrict__ ca2_w1,
    const float* __restrict__ kw2a, const float* __restrict__ kw2b,
    float* __restrict__ KP1, float* __restrict__ KP2,
    unsigned short* __restrict__ HID1, unsigned short* __restrict__ HID2){
  __shared__ unsigned short lA[4096], lB[4096];
  __shared__ float kp[2][32][9];
  const int z = blockIdx.z;
  const int tid = threadIdx.x;
  const int wid = tid>>6, lane = tid&63;
  const int l15 = lane&15, lkb = lane>>4;

  if (z < 2){
    const int it = blockIdx.x, jc = blockIdx.y;
    const float* kw1 = z ? k2_w1 : k1_w1;
    const float* kw2 = z ? kw2b : kw2a;
    float* KP        = z ? KP2 : KP1;
    const int m0 = it*32, n0 = jc*32;
    f32x4 acc = {};
    gemm32(deg, kw1, m0, n0, 512, tid, lA, lB, acc);

    const int wr = (wid>>1)*16, wc2 = wid&1;   // wave col-half (0/1)
    const int col = jc*32 + wc2*16 + l15;
    float w[9];
    #pragma unroll
    for (int t=0;t<9;t++) w[t] = kw2[t*512 + col];
    #pragma unroll
    for (int r=0;r<4;r++){
      const float v = lrelu_f(acc[r]);
      const int row = wr + lkb*4 + r;
      #pragma unroll
      for (int t=0;t<9;t++){
        float q = v*w[t];
        q += __shfl_xor(q,1); q += __shfl_xor(q,2);
        q += __shfl_xor(q,4); q += __shfl_xor(q,8);
        if (l15==0) kp[wc2][row][t] = q;
      }
    }
    __syncthreads();
    for (int i = tid; i < 288; i += 256){
      const int row = i/9, t = i - row*9;
      KP[((size_t)jc*512 + m0 + row)*9 + t] = kp[0][row][t] + kp[1][row][t];
    }
  } else {
    if (blockIdx.y >= 2) return;
    const float* caw = (z==2) ? ca1_w1 : ca2_w1;   // [64 h][512 c]
    unsigned short* HID = (z==2) ? HID1 : HID2;
    const int m0 = blockIdx.x*32, n0 = blockIdx.y*32;
    f32x4 acc = {};
    gemm32(DEGT, caw, m0, n0, 512, tid, lA, lB, acc);
    const int wr = (wid>>1)*16, wc = (wid&1)*16;
    #pragma unroll
    for (int r=0;r<4;r++){
      const int row = m0 + wr + lkb*4 + r;
      const int col = n0 + wc + l15;
      HID[(size_t)row*64 + col] = f2bf(lrelu_f(acc[r]));
    }
  }
}

// ==== fused: ATT GEMMs (blocks 0..127) + dwconv1 (blocks 128..639) ===========
__global__ __launch_bounds__(256) void k_att_dw(
    const float* __restrict__ ca1_w2, const float* __restrict__ ca2_w2,
    const unsigned short* __restrict__ HID1, const unsigned short* __restrict__ HID2,
    float* __restrict__ ATT1, float* __restrict__ ATT2,
    const float* __restrict__ xin, const float* __restrict__ KP1,
    unsigned short* __restrict__ DWLT, unsigned short* __restrict__ XTP){
  __shared__ __align__(16) unsigned char smem[16640];
  const int tid = threadIdx.x;
  int bid = blockIdx.x;
  if (bid < 128){
    unsigned short* lA = (unsigned short*)smem;       // 2 x 2048 us
    unsigned short* lB = lA + 4096;
    const int b = bid>>6, t6 = bid&63;
    const float* caw          = b ? ca2_w2 : ca1_w2;  // [512 c][64 h] f32
    const unsigned short* HID = b ? HID2 : HID1;      // [512 px][64 h] bf16
    float* ATT                = b ? ATT2 : ATT1;
    const int m0 = (t6>>3)*64, n0 = (t6&7)*64;
    f32x4 acc[2][2] = {};
    gemm64(caw, HID, m0, n0, 64, tid, lA, lB, acc);
    const int wid = tid>>6, lane = tid&63;
    const int wr = (wid>>1)*32, wc = (wid&1)*32;
    const int l15 = lane&15, lkb = lane>>4;
    #pragma unroll
    for (int mi=0;mi<2;mi++)
      #pragma unroll
      for (int ni=0;ni<2;ni++){
        const int row = m0 + wr + mi*16 + lkb*4;
        const int col = n0 + wc + ni*16 + l15;
        #pragma unroll
        for (int r=0;r<4;r++)
          ATT[(size_t)(row+r)*512 + col] = 1.f/(1.f + expf(-acc[mi][ni][r]));
      }
  } else {
    bid -= 128;
    const int c = bid;
    // zero XTP halo border once (grid-strided over dw blocks)
    {
      const int idx = bid*256 + tid;
      if (idx < 12800){
        const int si = idx>>7, wi = idx&127;
        int slot;
        if (si < 34) slot = si;
        else if (si < 68) slot = 578 + (si-34);
        else if (si < 84) slot = (si-67)*34;
        else slot = (si-83)*34 + 33;
        ushort4v zz = {};
        *(ushort4v*)(XTP + (size_t)slot*512 + wi*4) = zz;
      }
    }
    float* plane = (float*)smem;     // 612
    float* ks = plane + 612;         // 9
    for (int i=tid;i<612;i+=256) plane[i]=0.f;
    if (tid<9){
      float s=0.f;
      #pragma unroll
      for (int jc=0;jc<16;jc++) s += KP1[((size_t)jc*512 + c)*9 + tid];
      ks[tid]=s;
    }
    #pragma unroll
    for (int q=0;q<2;q++){
      const int px = tid + q*256;
      plane[((px>>5)+1)*34 + (px&31)+1] = xin[(size_t)c*512 + px];
    }
    __syncthreads();
    #pragma unroll
    for (int q=0;q<2;q++){
      const int px = tid + q*256;
      const int iy = px>>5, ix = px&31;
      float s = 0.f;
      #pragma unroll
      for (int dy=0;dy<3;dy++)
        #pragma unroll
        for (int dx=0;dx<3;dx++)
          s += plane[(iy+dy)*34 + ix+dx]*ks[dy*3+dx];
      DWLT[(size_t)px*512 + c] = f2bf(lrelu_f(s));
    }
  }
}

// ==== fused: reduce 18 bf16 conv partials + bias + lrelu, then dw2 -> yt =====
__global__ __launch_bounds__(512) void k_dwconv_red(const unsigned short* __restrict__ part,
    const float* __restrict__ bias, const float* __restrict__ KP,
    unsigned short* __restrict__ yt, int nchunks){
  const int c = blockIdx.x;
  const int p = threadIdx.x;
  const int iy = p>>5, ix = p&31;
  __shared__ float plane[18*34];
  __shared__ float ks[9];
  for (int i=p;i<18*34;i+=512) plane[i]=0.f;
  if (p < 9){
    float s = 0.f;
    #pragma unroll
    for (int jc=0;jc<16;jc++) s += KP[((size_t)jc*512 + c)*9 + p];
    ks[p] = s;
  }
  __syncthreads();
  if (p < 128){
    const float b = bias[c];
    float4 a4 = {b,b,b,b};
    for (int s=0;s<nchunks;s++){
      const ushort4v v = ((const ushort4v*)(part + (size_t)s*262144 + c*512))[p];
      a4.x += bf2f(v.x); a4.y += bf2f(v.y); a4.z += bf2f(v.z); a4.w += bf2f(v.w);
    }
    a4.x = lrelu_f(a4.x); a4.y = lrelu_f(a4.y);
    a4.z = lrelu_f(a4.z); a4.w = lrelu_f(a4.w);
    const int px0 = p*4;
    float* dst = &plane[((px0>>5)+1)*34 + (px0&31)+1];
    dst[0]=a4.x; dst[1]=a4.y; dst[2]=a4.z; dst[3]=a4.w;
  }
  __syncthreads();
  float s = 0.f;
  #pragma unroll
  for (int dy=0;dy<3;dy++)
    #pragma unroll
    for (int dx=0;dx<3;dx++)
      s += plane[(iy+dy)*34 + ix+dx]*ks[dy*3+dx];
  yt[(size_t)p*512 + c] = f2bf(lrelu_f(s));
}

// ==== pointwise GEMM 32x32-tile, f32 A inline; OUT -> XTP halo ===============
__global__ __launch_bounds__(256) void k_pw(
    const float* __restrict__ A, const unsigned short* __restrict__ Bt,
    const float* __restrict__ bias,
    const float* __restrict__ E1, const float* __restrict__ E2,
    unsigned short* __restrict__ XTP){
  __shared__ unsigned short lA[4096], lB[4096];
  __shared__ float tile[32][33];
  const int tid = threadIdx.x;
  const int wid = tid>>6, lane = tid&63;
  const int M0 = blockIdx.x*32, N0 = blockIdx.y*32;

  f32x4 acc = {};
  gemm32(A, Bt, M0, N0, 512, tid, lA, lB, acc);

  const int wr = (wid>>1)*16, wc = (wid&1)*16;
  const int l15 = lane&15, lkb = lane>>4;
  #pragma unroll
  for (int r=0;r<4;r++){
    const int rl = wr + lkb*4 + r;
    const int cl = wc + l15;
    const int rr = M0 + rl, col = N0 + cl;
    float v = acc[r] + bias[rr] + E1[(size_t)rr*512+col]*E2[(size_t)rr*512+col];
    tile[rl][cl] = lrelu_f(v);
  }
  __syncthreads();
  const int pr = tid>>3, q = tid&7;
  const int p = N0 + pr;
  const int slot = ((p>>5)+1)*34 + (p&31) + 1;
  ushort4v o;
  o.x = f2bf(tile[q*4+0][pr]); o.y = f2bf(tile[q*4+1][pr]);
  o.z = f2bf(tile[q*4+2][pr]); o.w = f2bf(tile[q*4+3][pr]);
  *(ushort4v*)(XTP + (size_t)slot*512 + M0 + q*4) = o;
}

// ===== conv 3x3 MFMA GEMM 64x128 tile, BK=64, global_load_lds staging ========
template<int KCH>   // 256
__global__ __launch_bounds__(256) void k_mfma_conv(
    const unsigned short* __restrict__ WB,
    const unsigned short* __restrict__ XTP,
    unsigned short* __restrict__ part){
  __shared__ __attribute__((aligned(16))) unsigned short lA[2][4096];
  __shared__ __attribute__((aligned(16))) unsigned short lB[2][8192];
  const int tid = threadIdx.x;
  const int wid = tid>>6, lane = tid&63;
  const int m0 = blockIdx.x*64, n0 = blockIdx.y*128;
  const int k0 = blockIdx.z*KCH;

  const int wrow = wid*8 + (lane>>3);
  const int clin = lane&7;
  const unsigned short* asrc[2];
  #pragma unroll
  for (int j=0;j<2;j++){
    const int r = j*32 + wrow;
    asrc[j] = WB + (size_t)(m0+r)*4608 + k0 + (clin ^ (r&7))*8;
  }
  int bpy[4], bpx[4], bchk[4];
  #pragma unroll
  for (int j=0;j<4;j++){
    const int r = j*32 + wrow;
    const int pp = n0 + r;
    bpy[j] = pp>>5; bpx[j] = pp&31;
    bchk[j] = (clin ^ (r&7))*8;
  }

  const int wr = (wid>>1)*32, wc = (wid&1)*64;
  const int l15 = lane&15, lkb = lane>>4;
  int aoff[2][2], boff[4][2];
  #pragma unroll
  for (int s=0;s<2;s++){
    const int Ra = wr + s*16 + l15;
    #pragma unroll
    for (int h=0;h<2;h++) aoff[s][h] = Ra*64 + 8*((lkb+4*h) ^ (Ra&7));
  }
  #pragma unroll
  for (int u=0;u<4;u++){
    const int Rb = wc + u*16 + l15;
    #pragma unroll
    for (int h=0;h<2;h++) boff[u][h] = Rb*64 + 8*((lkb+4*h) ^ (Rb&7));
  }

  auto stage = [&](int buf, int st){
    #pragma unroll
    for (int j=0;j<2;j++)
      gload16(asrc[j] + st*64, &lA[buf][j*2048 + wid*512]);
    const int k = k0 + st*64;
    const int t = k>>9;
    const int dy = t/3, dx = t - dy*3;
    const int kc = k & 511;
    #pragma unroll
    for (int j=0;j<4;j++){
      const int slot = (bpy[j]+dy)*34 + bpx[j]+dx;
      gload16(XTP + (size_t)slot*512 + kc + bchk[j],
              &lB[buf][j*2048 + wid*512]);
    }
  };

  constexpr int NST = KCH/64;
  f32x4 acc[2][4] = {};
  stage(0, 0);
  __syncthreads();
  #pragma unroll
  for (int st=0; st<NST; ++st){
    const int cur = st&1;
    if (st+1 < NST) stage(cur^1, st+1);
    bf16x8 af[2][2], bfr[4][2];
    #pragma unroll
    for (int s=0;s<2;s++)
      #pragma unroll
      for (int h=0;h<2;h++) af[s][h] = *(const bf16x8*)(&lA[cur][aoff[s][h]]);
    #pragma unroll
    for (int u=0;u<4;u++)
      #pragma unroll
      for (int h=0;h<2;h++) bfr[u][h] = *(const bf16x8*)(&lB[cur][boff[u][h]]);
    #pragma unroll
    for (int h=0;h<2;h++)
      #pragma unroll
      for (int s=0;s<2;s++)
        #pragma unroll
        for (int u=0;u<4;u++)
          acc[s][u] = __builtin_amdgcn_mfma_f32_16x16x32_bf16(af[s][h], bfr[u][h], acc[s][u], 0,0,0);
    __syncthreads();
  }

  unsigned short* pbase = part + (size_t)blockIdx.z*262144;
  #pragma unroll
  for (int s=0;s<2;s++)
    #pragma unroll
    for (int u=0;u<4;u++){
      const int row = m0 + wr + s*16 + lkb*4;
      const int col = n0 + wc + u*16 + l15;
      #pragma unroll
      for (int r=0;r<4;r++)
        pbase[(size_t)(row+r)*512 + col] = f2bf(acc[s][u][r]);
    }
}

// ===== final reduce: bias + bf16 partials + residual =========================
__global__ __launch_bounds__(256) void k_reduce_final(const unsigned short* __restrict__ part,
    const float* __restrict__ bias, const float* __restrict__ res,
    float* __restrict__ y, int nchunks){
  const int i = blockIdx.x*256 + threadIdx.x;
  const int o = i>>7;
  const float b = bias[o];
  float4 a4 = {b,b,b,b};
  for (int s=0;s<nchunks;s++){
    const ushort4v v = ((const ushort4v*)part)[(size_t)s*65536 + i];
    a4.x += bf2f(v.x); a4.y += bf2f(v.y); a4.z += bf2f(v.z); a4.w += bf2f(v.w);
  }
  const float4 rv = ((const float4*)res)[i];
  a4.x += rv.x; a4.y += rv.y; a4.z += rv.z; a4.w += rv.w;
  ((float4*)y)[i] = a4;
}

extern "C" void kernel_launch(void* const* d_in, const int* in_sizes, int n_in,
                              void* d_out, int out_size, void* d_ws, size_t ws_size,
                              hipStream_t stream) {
  (void)in_sizes; (void)n_in; (void)out_size; (void)ws_size;
  const float* xin    = (const float*)d_in[0];
  const float* deg    = (const float*)d_in[1];
  const float* k1_w1  = (const float*)d_in[2];
  const float* k1_w2  = (const float*)d_in[3];
  const float* p1_w   = (const float*)d_in[4];
  const float* p1_b   = (const float*)d_in[5];
  const float* ca1_w1 = (const float*)d_in[6];
  const float* ca1_w2 = (const float*)d_in[7];
  const float* conv1_w= (const float*)d_in[8];
  const float* conv1_b= (const float*)d_in[9];
  const float* k2_w1  = (const float*)d_in[10];
  const float* k2_w2  = (const float*)d_in[11];
  const float* p2_w   = (const float*)d_in[12];
  const float* p2_b   = (const float*)d_in[13];
  const float* ca2_w1 = (const float*)d_in[14];
  const float* ca2_w2 = (const float*)d_in[15];
  const float* conv2_w= (const float*)d_in[16];
  const float* conv2_b= (const float*)d_in[17];
  float* out = (float*)d_out;

  const int NS = 18;                       // conv split-K chunks (KCH=256)

  // ---- workspace (cursor in floats) ----
  float* ws = (float*)d_ws;
  unsigned short* PART = (unsigned short*)ws;  ws += (size_t)NS*131072;  // exact
  float* KP1  = ws;  ws += 73728;          // 16 jc x 512 c x 9 t
  float* KP2  = ws;  ws += 73728;
  float* ATT1 = ws;  ws += 262144;
  float* ATT2 = ws;  ws += 262144;
  unsigned short* HID1 = (unsigned short*)ws; ws += 16384;   // 32768 us
  unsigned short* HID2 = (unsigned short*)ws; ws += 16384;
  unsigned short* DEGT = (unsigned short*)ws; ws += 131072;  // slack ok
  unsigned short* XTP  = (unsigned short*)ws; ws += 156672;  // 313344 us
  unsigned short* DWLT = (unsigned short*)ws; ws += 131072;
  unsigned short* WB1  = (unsigned short*)ws; ws += 1179648;
  unsigned short* WB2  = (unsigned short*)ws; ws += 1179648;

  // 1. light pack: DEGT + conv weight reorder
  k_pack_lite<<<4864,256,0,stream>>>(deg, conv1_w, conv2_w, DEGT, WB1, WB2);

  // 2. pre: kern partials (z=0,1) + HID (z=2,3)
  k_pre<<<dim3(16,16,4),256,0,stream>>>(deg, DEGT, k1_w1, k2_w1,
      ca1_w1, ca2_w1, k1_w2, k2_w2, KP1, KP2, HID1, HID2);

  // 3. fused ATT GEMMs + dwconv1 (+ XTP border zero)
  k_att_dw<<<640,256,0,stream>>>(ca1_w2, ca2_w2, HID1, HID2, ATT1, ATT2,
      xin, KP1, DWLT, XTP);

  // 4. pointwise 1 (+bias+deg*att+lrelu) -> XTP interior
  k_pw<<<dim3(16,16),256,0,stream>>>(p1_w, DWLT, p1_b, deg, ATT1, XTP);
  // 5. conv1 3x3
  k_mfma_conv<256><<<dim3(8,4,18),256,0,stream>>>(WB1, XTP, PART);
  // 6. fused reduce+lrelu+depthwise (da_conv2) -> DWLT
  k_dwconv_red<<<512,512,0,stream>>>(PART, conv1_b, KP2, DWLT, NS);
  // 7. pointwise 2 -> XTP interior
  k_pw<<<dim3(16,16),256,0,stream>>>(p2_w, DWLT, p2_b, deg, ATT2, XTP);
  // 8. conv2 3x3
  k_mfma_conv<256><<<dim3(8,4,18),256,0,stream>>>(WB2, XTP, PART);
  // 9. final reduce + bias + residual
  k_reduce_final<<<256,256,0,stream>>>(PART, conv2_b, xin, out, NS);
}

// Round 16
// 81.701 us; speedup vs baseline: 1.0581x; 1.0581x over previous
//
#include <hip/hip_runtime.h>
#include <hip/hip_bf16.h>

typedef __attribute__((ext_vector_type(8))) unsigned short ushort8;
typedef __attribute__((ext_vector_type(8))) __bf16 bf16x8;
typedef __attribute__((ext_vector_type(4))) float f32x4;
typedef __attribute__((ext_vector_type(4))) unsigned short ushort4v;

__device__ __forceinline__ float lrelu_f(float v){ return v > 0.f ? v : 0.1f*v; }

__device__ __forceinline__ unsigned short f2bf(float v){
  unsigned u = __float_as_uint(v);
  unsigned r = (u + 0x7fffu + ((u>>16)&1u)) >> 16;
  return (unsigned short)r;
}
__device__ __forceinline__ float bf2f(unsigned short u){
  return __uint_as_float(((unsigned)u)<<16);
}

__device__ __forceinline__ void gload16(const void* g, void* l){
  __builtin_amdgcn_global_load_lds(
    (const __attribute__((address_space(1))) unsigned int*)g,
    (__attribute__((address_space(3))) unsigned int*)l, 16, 0, 0);
}

__device__ __forceinline__ void packq(const float* __restrict__ s,
                                      unsigned short* __restrict__ d, int i){
  const float4 v = ((const float4*)s)[i];
  ushort4v o; o.x=f2bf(v.x); o.y=f2bf(v.y); o.z=f2bf(v.z); o.w=f2bf(v.w);
  *(ushort4v*)(d + (size_t)i*4) = o;
}

// ============ pack: small weights + deg (WB reorder moved to k_mgemm_pre) ====
__global__ __launch_bounds__(256) void k_pack_all(
  const float* __restrict__ k1_w1, const float* __restrict__ k2_w1,
  const float* __restrict__ p1_w,  const float* __restrict__ p2_w,
  const float* __restrict__ ca1_w1,const float* __restrict__ ca1_w2,
  const float* __restrict__ ca2_w1,const float* __restrict__ ca2_w2,
  const float* __restrict__ deg,
  unsigned short* __restrict__ K1B, unsigned short* __restrict__ K2B,
  unsigned short* __restrict__ P1B, unsigned short* __restrict__ P2B,
  unsigned short* __restrict__ CA1A,unsigned short* __restrict__ CA1B,
  unsigned short* __restrict__ CA2A,unsigned short* __restrict__ CA2B,
  unsigned short* __restrict__ DEGB,unsigned short* __restrict__ DEGT){
  int i = blockIdx.x*256 + threadIdx.x;
  if (i < 65536){ packq(k1_w1, K1B, i); return; } i -= 65536;
  if (i < 65536){ packq(k2_w1, K2B, i); return; } i -= 65536;
  if (i < 65536){ packq(p1_w,  P1B, i); return; } i -= 65536;
  if (i < 65536){ packq(p2_w,  P2B, i); return; } i -= 65536;
  if (i < 8192){ packq(ca1_w1, CA1A, i); return; } i -= 8192;
  if (i < 8192){ packq(ca1_w2, CA1B, i); return; } i -= 8192;
  if (i < 8192){ packq(ca2_w1, CA2A, i); return; } i -= 8192;
  if (i < 8192){ packq(ca2_w2, CA2B, i); return; } i -= 8192;
  if (i < 65536){ packq(deg, DEGB, i); return; } i -= 65536;
  if (i < 65536){                      // DEGT: bf16 transpose of deg
    const int j = i*4; const int p = j>>9, c = j&511;
    ushort4v o;
    o.x = f2bf(deg[(size_t)(c+0)*512 + p]);
    o.y = f2bf(deg[(size_t)(c+1)*512 + p]);
    o.z = f2bf(deg[(size_t)(c+2)*512 + p]);
    o.w = f2bf(deg[(size_t)(c+3)*512 + p]);
    *(ushort4v*)(DEGT + (size_t)j) = o;
  }
}

// ==== 32x32 GEMM core: 4 waves = 4 quadrants, BK=64, dbuf single-barrier ====
__device__ __forceinline__ void gemm32(
    const unsigned short* __restrict__ A, const unsigned short* __restrict__ Bt,
    int m0, int n0, int K, int tid,
    unsigned short* lA, unsigned short* lB, f32x4& acc){
  const int wid = tid>>6, lane = tid&63;
  const int half = tid>>7, st_ = tid&127;
  const int srow = st_>>2, skb = st_&3;
  const unsigned short* gS = (half ? Bt + (size_t)(n0+srow)*K
                                   : A  + (size_t)(m0+srow)*K);
  unsigned short* lS = half ? lB : lA;
  const int soff0 = srow*64 + 8*(skb ^ (srow&7));
  const int soff1 = srow*64 + 8*((skb+4) ^ (srow&7));

  const int wr = (wid>>1)*16, wc = (wid&1)*16;
  const int l15 = lane&15, lkb = lane>>4;
  int aoff[2], boff[2];
  #pragma unroll
  for (int h=0;h<2;h++){
    const int Ra = wr + l15;
    aoff[h] = Ra*64 + 8*((lkb+4*h) ^ (Ra&7));
    const int Rb = wc + l15;
    boff[h] = Rb*64 + 8*((lkb+4*h) ^ (Rb&7));
  }

  const int nst = K>>6;
  ushort8 r0 = *(const ushort8*)(gS + skb*8);
  ushort8 r1 = *(const ushort8*)(gS + (skb+4)*8);
  *(ushort8*)(lS + soff0) = r0;
  *(ushort8*)(lS + soff1) = r1;
  if (nst > 1){
    r0 = *(const ushort8*)(gS + 64 + skb*8);
    r1 = *(const ushort8*)(gS + 64 + (skb+4)*8);
  }
  __syncthreads();
  for (int st=0; st<nst; ++st){
    const int cur = (st&1)*2048;
    bf16x8 af[2], bf[2];
    #pragma unroll
    for (int h=0;h<2;h++){
      af[h] = *(const bf16x8*)(lA + cur + aoff[h]);
      bf[h] = *(const bf16x8*)(lB + cur + boff[h]);
    }
    if (st+1 < nst){
      const int nxt = ((st+1)&1)*2048;
      *(ushort8*)(lS + nxt + soff0) = r0;
      *(ushort8*)(lS + nxt + soff1) = r1;
      if (st+2 < nst){
        r0 = *(const ushort8*)(gS + (size_t)(st+2)*64 + skb*8);
        r1 = *(const ushort8*)(gS + (size_t)(st+2)*64 + (skb+4)*8);
      }
    }
    #pragma unroll
    for (int h=0;h<2;h++)
      acc = __builtin_amdgcn_mfma_f32_16x16x32_bf16(af[h], bf[h], acc, 0,0,0);
    __syncthreads();
  }
}

// ==== batched pre-GEMMs, 32x32 tiles + WB reorder in idle blocks:
//  z=0,1: TMP{1,2}=lrelu(deg@kw1^T) f32 [512][512]   (x=16,y=16)
//  z=2,3 y<2: HID{1,2}=lrelu(DEGT@ca_w1^T) bf16 [512][64]
//  z=2,3 y>=2: WB{1,2} conv weight reorder [o][t*512+ci] = w[o][ci*9+t]
__global__ __launch_bounds__(256) void k_mgemm_pre(
    const unsigned short* __restrict__ DEGB, const unsigned short* __restrict__ DEGT,
    const unsigned short* __restrict__ K1B,  const unsigned short* __restrict__ K2B,
    const unsigned short* __restrict__ CA1A, const unsigned short* __restrict__ CA2A,
    const float* __restrict__ conv1_w, const float* __restrict__ conv2_w,
    float* __restrict__ TMP1, float* __restrict__ TMP2,
    unsigned short* __restrict__ HID1, unsigned short* __restrict__ HID2,
    unsigned short* __restrict__ WB1, unsigned short* __restrict__ WB2){
  const int z = blockIdx.z;
  if (z >= 2 && blockIdx.y >= 2){
    // conv weight reorder on otherwise-idle blocks (224 blocks per z)
    const float* src      = (z==2) ? conv1_w : conv2_w;
    unsigned short* dst   = (z==2) ? WB1 : WB2;
    const int base = (((blockIdx.y-2)*16 + blockIdx.x)*256) + threadIdx.x;
    for (int i = base; i < 589824; i += 57344){
      const int o_ = i/1152; const int r4 = (i - o_*1152)*4;
      const int t = r4>>9; const int ci = r4&511;
      const float* s = src + (size_t)o_*4608;
      ushort4v o;
      o.x = f2bf(s[(ci+0)*9 + t]); o.y = f2bf(s[(ci+1)*9 + t]);
      o.z = f2bf(s[(ci+2)*9 + t]); o.w = f2bf(s[(ci+3)*9 + t]);
      *(ushort4v*)(dst + (size_t)o_*4608 + r4) = o;
    }
    return;
  }
  const unsigned short* A  = (z < 2) ? DEGB : DEGT;
  const unsigned short* Bt = (z==0) ? K1B : (z==1) ? K2B : (z==2) ? CA1A : CA2A;
  __shared__ unsigned short lA[4096], lB[4096];
  const int tid = threadIdx.x;
  const int m0 = blockIdx.x*32, n0 = blockIdx.y*32;
  f32x4 acc = {};
  gemm32(A, Bt, m0, n0, 512, tid, lA, lB, acc);

  const int wid = tid>>6, lane = tid&63;
  const int wr = (wid>>1)*16, wc = (wid&1)*16;
  const int l15 = lane&15, lkb = lane>>4;
  #pragma unroll
  for (int r=0;r<4;r++){
    const int row = m0 + wr + lkb*4 + r;
    const int col = n0 + wc + l15;
    const float v = lrelu_f(acc[r]);
    if (z==0)      TMP1[(size_t)row*512 + col] = v;
    else if (z==1) TMP2[(size_t)row*512 + col] = v;
    else if (z==2) HID1[(size_t)row*64 + col] = f2bf(v);
    else           HID2[(size_t)row*64 + col] = f2bf(v);
  }
}

// ======= 64x64 MFMA GEMM core (for ATT K=64 GEMM), 4 waves, dbuf ========
__device__ __forceinline__ void gemm64(
    const unsigned short* __restrict__ A, const unsigned short* __restrict__ Bt,
    int m0, int n0, int K, int tid,
    unsigned short* lA, unsigned short* lB, f32x4 acc[2][2]){
  const int wid = tid>>6, lane = tid&63;
  const int srow = tid>>2, skb = tid&3;
  const unsigned short* gA = A  + (size_t)(m0+srow)*K + skb*8;
  const unsigned short* gB = Bt + (size_t)(n0+srow)*K + skb*8;
  const int soff = srow*32 + 8*(skb ^ (srow&3));
  const int wr = (wid>>1)*32, wc = (wid&1)*32;
  const int l15 = lane&15, lkb = lane>>4;
  int aoff[2], boff[2];
  #pragma unroll
  for (int s=0;s<2;s++){
    const int Ra = wr + s*16 + l15;
    aoff[s] = Ra*32 + 8*(lkb ^ (Ra&3));
    const int Rb = wc + s*16 + l15;
    boff[s] = Rb*32 + 8*(lkb ^ (Rb&3));
  }
  const int nst = K>>5;
  ushort8 ra = *(const ushort8*)gA;
  ushort8 rb = *(const ushort8*)gB;
  *(ushort8*)(lA + soff) = ra;
  *(ushort8*)(lB + soff) = rb;
  if (nst > 1){ ra = *(const ushort8*)(gA+32); rb = *(const ushort8*)(gB+32); }
  __syncthreads();
  for (int st=0; st<nst; ++st){
    const int cur = (st&1)*2048;
    bf16x8 af[2], bfr[2];
    #pragma unroll
    for (int s=0;s<2;s++){
      af[s]  = *(const bf16x8*)(lA + cur + aoff[s]);
      bfr[s] = *(const bf16x8*)(lB + cur + boff[s]);
    }
    if (st+1 < nst){
      const int nxt = ((st+1)&1)*2048;
      *(ushort8*)(lA + nxt + soff) = ra;
      *(ushort8*)(lB + nxt + soff) = rb;
      if (st+2 < nst){
        ra = *(const ushort8*)(gA + (size_t)(st+2)*32);
        rb = *(const ushort8*)(gB + (size_t)(st+2)*32);
      }
    }
    #pragma unroll
    for (int mi=0;mi<2;mi++)
      #pragma unroll
      for (int ni=0;ni<2;ni++)
        acc[mi][ni] = __builtin_amdgcn_mfma_f32_16x16x32_bf16(af[mi], bfr[ni], acc[mi][ni], 0,0,0);
    __syncthreads();
  }
}

// ==== batched: z=0,1 kern_gen ; z=2,3 ATT ; idle z=2,x>=64: XTP border zero ==
__global__ __launch_bounds__(256) void k_kern_att(
    const float* __restrict__ TMP1, const float* __restrict__ TMP2,
    const float* __restrict__ kw2a, const float* __restrict__ kw2b,
    const unsigned short* __restrict__ CA1B, const unsigned short* __restrict__ CA2B,
    const unsigned short* __restrict__ HID1, const unsigned short* __restrict__ HID2,
    float* __restrict__ kern0, float* __restrict__ kern1,
    float* __restrict__ ATT1, float* __restrict__ ATT2,
    unsigned short* __restrict__ XTP){
  const int z = blockIdx.z;
  const int tid = threadIdx.x;
  if (z < 2){
    const float* tmp  = z ? TMP2 : TMP1;
    const float* kw2  = z ? kw2b : kw2a;
    float* kern       = z ? kern1 : kern0;
    const int i = blockIdx.x*4 + (tid>>6);
    const int lane = tid&63;
    float acc[9];
    #pragma unroll
    for (int q=0;q<9;q++) acc[q]=0.f;
    for (int j=lane; j<512; j+=64){
      const float t = tmp[i*512 + j];
      #pragma unroll
      for (int q=0;q<9;q++) acc[q] += t*kw2[q*512 + j];
    }
    #pragma unroll
    for (int q=0;q<9;q++){
      float v = acc[q];
      #pragma unroll
      for (int off=32; off>0; off>>=1) v += __shfl_down(v, off);
      if (lane==0) kern[i*9+q] = v;
    }
  } else {
    if (blockIdx.x >= 64){
      if (z==2){
        // XTP halo border zero (100 slots x 512 ch = 12800 quads)
        const int idx = (blockIdx.x-64)*256 + tid;
        if (idx < 12800){
          const int si = idx>>7, wi = idx&127;
          int slot;
          if (si < 34) slot = si;
          else if (si < 68) slot = 578 + (si-34);
          else if (si < 84) slot = (si-67)*34;
          else slot = (si-83)*34 + 33;
          ushort4v zz = {};
          *(ushort4v*)(XTP + (size_t)slot*512 + wi*4) = zz;
        }
      }
      return;
    }
    const unsigned short* A  = (z==2) ? CA1B : CA2B;   // [512][64]
    const unsigned short* Bt = (z==2) ? HID1 : HID2;   // [512][64]
    float* ATT               = (z==2) ? ATT1 : ATT2;
    __shared__ unsigned short lA[4096], lB[4096];
    const int m0 = (blockIdx.x>>3)*64, n0 = (blockIdx.x&7)*64;
    f32x4 acc[2][2] = {};
    gemm64(A, Bt, m0, n0, 64, tid, lA, lB, acc);
    const int wid = tid>>6, lane = tid&63;
    const int wr = (wid>>1)*32, wc = (wid&1)*32;
    const int l15 = lane&15, lkb = lane>>4;
    #pragma unroll
    for (int mi=0;mi<2;mi++)
      #pragma unroll
      for (int ni=0;ni<2;ni++){
        const int row = m0 + wr + mi*16 + lkb*4;
        const int col = n0 + wc + ni*16 + l15;
        #pragma unroll
        for (int r=0;r<4;r++)
          ATT[(size_t)(row+r)*512 + col] = 1.f/(1.f + expf(-acc[mi][ni][r]));
      }
  }
}

// ==== depthwise 3x3 (SAME) + lrelu, OUT transposed bf16 [px][ch] =============
__global__ __launch_bounds__(512) void k_dwconv(const float* __restrict__ x,
    const float* __restrict__ kern, unsigned short* __restrict__ yt){
  const int c = blockIdx.x;
  const int p = threadIdx.x;
  const int iy = p>>5, ix = p&31;
  __shared__ float plane[18*34];
  for (int i=p;i<18*34;i+=512) plane[i]=0.f;
  __syncthreads();
  plane[(iy+1)*34 + ix+1] = x[c*512 + p];
  __syncthreads();
  const float* kp = kern + c*9;
  float s = 0.f;
  #pragma unroll
  for (int dy=0;dy<3;dy++)
    #pragma unroll
    for (int dx=0;dx<3;dx++)
      s += plane[(iy+dy)*34 + ix+dx]*kp[dy*3+dx];
  yt[(size_t)p*512 + c] = f2bf(lrelu_f(s));
}

// ==== fused: reduce 18 bf16 conv partials + bias + lrelu, then dw -> yt ======
__global__ __launch_bounds__(512) void k_dwconv_red(const unsigned short* __restrict__ part,
    const float* __restrict__ bias, const float* __restrict__ kern,
    unsigned short* __restrict__ yt, int nchunks){
  const int c = blockIdx.x;
  const int p = threadIdx.x;
  const int iy = p>>5, ix = p&31;
  __shared__ float plane[18*34];
  for (int i=p;i<18*34;i+=512) plane[i]=0.f;
  __syncthreads();
  if (p < 128){
    const float b = bias[c];
    float4 a4 = {b,b,b,b};
    for (int s=0;s<nchunks;s++){
      const ushort4v v = ((const ushort4v*)(part + (size_t)s*262144 + c*512))[p];
      a4.x += bf2f(v.x); a4.y += bf2f(v.y); a4.z += bf2f(v.z); a4.w += bf2f(v.w);
    }
    a4.x = lrelu_f(a4.x); a4.y = lrelu_f(a4.y);
    a4.z = lrelu_f(a4.z); a4.w = lrelu_f(a4.w);
    const int px0 = p*4;
    float* dst = &plane[((px0>>5)+1)*34 + (px0&31)+1];
    dst[0]=a4.x; dst[1]=a4.y; dst[2]=a4.z; dst[3]=a4.w;
  }
  __syncthreads();
  const float* kp = kern + c*9;
  float s = 0.f;
  #pragma unroll
  for (int dy=0;dy<3;dy++)
    #pragma unroll
    for (int dx=0;dx<3;dx++)
      s += plane[(iy+dy)*34 + ix+dx]*kp[dy*3+dx];
  yt[(size_t)p*512 + c] = f2bf(lrelu_f(s));
}

// ==== pointwise GEMM 32x32-tile, BK=64 (8 steps); OUT -> XTP halo ============
__global__ __launch_bounds__(256) void k_pw(
    const unsigned short* __restrict__ A, const unsigned short* __restrict__ Bt,
    const float* __restrict__ bias,
    const float* __restrict__ E1, const float* __restrict__ E2,
    unsigned short* __restrict__ XTP){
  __shared__ unsigned short lA[4096], lB[4096];
  __shared__ float tile[32][33];
  const int tid = threadIdx.x;
  const int wid = tid>>6, lane = tid&63;
  const int M0 = blockIdx.x*32, N0 = blockIdx.y*32;

  f32x4 acc = {};
  gemm32(A, Bt, M0, N0, 512, tid, lA, lB, acc);

  const int wr = (wid>>1)*16, wc = (wid&1)*16;
  const int l15 = lane&15, lkb = lane>>4;
  #pragma unroll
  for (int r=0;r<4;r++){
    const int rl = wr + lkb*4 + r;
    const int cl = wc + l15;
    const int rr = M0 + rl, col = N0 + cl;
    float v = acc[r] + bias[rr] + E1[(size_t)rr*512+col]*E2[(size_t)rr*512+col];
    tile[rl][cl] = lrelu_f(v);
  }
  __syncthreads();
  const int pr = tid>>3, q = tid&7;
  const int p = N0 + pr;
  const int slot = ((p>>5)+1)*34 + (p&31) + 1;
  ushort4v o;
  o.x = f2bf(tile[q*4+0][pr]); o.y = f2bf(tile[q*4+1][pr]);
  o.z = f2bf(tile[q*4+2][pr]); o.w = f2bf(tile[q*4+3][pr]);
  *(ushort4v*)(XTP + (size_t)slot*512 + M0 + q*4) = o;
}

// ===== conv 3x3 MFMA GEMM 64x128 tile, BK=64, global_load_lds staging ========
template<int KCH>   // 256
__global__ __launch_bounds__(256) void k_mfma_conv(
    const unsigned short* __restrict__ WB,
    const unsigned short* __restrict__ XTP,
    unsigned short* __restrict__ part){
  __shared__ __attribute__((aligned(16))) unsigned short lA[2][4096];
  __shared__ __attribute__((aligned(16))) unsigned short lB[2][8192];
  const int tid = threadIdx.x;
  const int wid = tid>>6, lane = tid&63;
  const int m0 = blockIdx.x*64, n0 = blockIdx.y*128;
  const int k0 = blockIdx.z*KCH;

  const int wrow = wid*8 + (lane>>3);
  const int clin = lane&7;
  const unsigned short* asrc[2];
  #pragma unroll
  for (int j=0;j<2;j++){
    const int r = j*32 + wrow;
    asrc[j] = WB + (size_t)(m0+r)*4608 + k0 + (clin ^ (r&7))*8;
  }
  int bpy[4], bpx[4], bchk[4];
  #pragma unroll
  for (int j=0;j<4;j++){
    const int r = j*32 + wrow;
    const int pp = n0 + r;
    bpy[j] = pp>>5; bpx[j] = pp&31;
    bchk[j] = (clin ^ (r&7))*8;
  }

  const int wr = (wid>>1)*32, wc = (wid&1)*64;
  const int l15 = lane&15, lkb = lane>>4;
  int aoff[2][2], boff[4][2];
  #pragma unroll
  for (int s=0;s<2;s++){
    const int Ra = wr + s*16 + l15;
    #pragma unroll
    for (int h=0;h<2;h++) aoff[s][h] = Ra*64 + 8*((lkb+4*h) ^ (Ra&7));
  }
  #pragma unroll
  for (int u=0;u<4;u++){
    const int Rb = wc + u*16 + l15;
    #pragma unroll
    for (int h=0;h<2;h++) boff[u][h] = Rb*64 + 8*((lkb+4*h) ^ (Rb&7));
  }

  auto stage = [&](int buf, int st){
    #pragma unroll
    for (int j=0;j<2;j++)
      gload16(asrc[j] + st*64, &lA[buf][j*2048 + wid*512]);
    const int k = k0 + st*64;
    const int t = k>>9;
    const int dy = t/3, dx = t - dy*3;
    const int kc = k & 511;
    #pragma unroll
    for (int j=0;j<4;j++){
      const int slot = (bpy[j]+dy)*34 + bpx[j]+dx;
      gload16(XTP + (size_t)slot*512 + kc + bchk[j],
              &lB[buf][j*2048 + wid*512]);
    }
  };

  constexpr int NST = KCH/64;
  f32x4 acc[2][4] = {};
  stage(0, 0);
  __syncthreads();
  #pragma unroll
  for (int st=0; st<NST; ++st){
    const int cur = st&1;
    if (st+1 < NST) stage(cur^1, st+1);
    bf16x8 af[2][2], bfr[4][2];
    #pragma unroll
    for (int s=0;s<2;s++)
      #pragma unroll
      for (int h=0;h<2;h++) af[s][h] = *(const bf16x8*)(&lA[cur][aoff[s][h]]);
    #pragma unroll
    for (int u=0;u<4;u++)
      #pragma unroll
      for (int h=0;h<2;h++) bfr[u][h] = *(const bf16x8*)(&lB[cur][boff[u][h]]);
    #pragma unroll
    for (int h=0;h<2;h++)
      #pragma unroll
      for (int s=0;s<2;s++)
        #pragma unroll
        for (int u=0;u<4;u++)
          acc[s][u] = __builtin_amdgcn_mfma_f32_16x16x32_bf16(af[s][h], bfr[u][h], acc[s][u], 0,0,0);
    __syncthreads();
  }

  unsigned short* pbase = part + (size_t)blockIdx.z*262144;
  #pragma unroll
  for (int s=0;s<2;s++)
    #pragma unroll
    for (int u=0;u<4;u++){
      const int row = m0 + wr + s*16 + lkb*4;
      const int col = n0 + wc + u*16 + l15;
      #pragma unroll
      for (int r=0;r<4;r++)
        pbase[(size_t)(row+r)*512 + col] = f2bf(acc[s][u][r]);
    }
}

// ===== final reduce: bias + bf16 partials + residual =========================
__global__ __launch_bounds__(256) void k_reduce_final(const unsigned short* __restrict__ part,
    const float* __restrict__ bias, const float* __restrict__ res,
    float* __restrict__ y, int nchunks){
  const int i = blockIdx.x*256 + threadIdx.x;
  const int o = i>>7;
  const float b = bias[o];
  float4 a4 = {b,b,b,b};
  for (int s=0;s<nchunks;s++){
    const ushort4v v = ((const ushort4v*)part)[(size_t)s*65536 + i];
    a4.x += bf2f(v.x); a4.y += bf2f(v.y); a4.z += bf2f(v.z); a4.w += bf2f(v.w);
  }
  const float4 rv = ((const float4*)res)[i];
  a4.x += rv.x; a4.y += rv.y; a4.z += rv.z; a4.w += rv.w;
  ((float4*)y)[i] = a4;
}

extern "C" void kernel_launch(void* const* d_in, const int* in_sizes, int n_in,
                              void* d_out, int out_size, void* d_ws, size_t ws_size,
                              hipStream_t stream) {
  (void)in_sizes; (void)n_in; (void)out_size; (void)ws_size;
  const float* xin    = (const float*)d_in[0];
  const float* deg    = (const float*)d_in[1];
  const float* k1_w1  = (const float*)d_in[2];
  const float* k1_w2  = (const float*)d_in[3];
  const float* p1_w   = (const float*)d_in[4];
  const float* p1_b   = (const float*)d_in[5];
  const float* ca1_w1 = (const float*)d_in[6];
  const float* ca1_w2 = (const float*)d_in[7];
  const float* conv1_w= (const float*)d_in[8];
  const float* conv1_b= (const float*)d_in[9];
  const float* k2_w1  = (const float*)d_in[10];
  const float* k2_w2  = (const float*)d_in[11];
  const float* p2_w   = (const float*)d_in[12];
  const float* p2_b   = (const float*)d_in[13];
  const float* ca2_w1 = (const float*)d_in[14];
  const float* ca2_w2 = (const float*)d_in[15];
  const float* conv2_w= (const float*)d_in[16];
  const float* conv2_b= (const float*)d_in[17];
  float* out = (float*)d_out;

  const int NS = 18;                       // conv split-K chunks (KCH=256)

  // ---- workspace ----
  float* ws = (float*)d_ws;
  unsigned short* PART = (unsigned short*)ws;
  ws += (size_t)NS*131072;                 // 9.4 MB
  float* TMP1 = (float*)PART;
  float* TMP2 = TMP1 + 262144;
  unsigned short* HID1 = (unsigned short*)(TMP2 + 262144);
  unsigned short* HID2 = HID1 + 32768;
  float* KERN1 = ws;  ws += 4608;
  float* KERN2 = ws;  ws += 4608;
  float* ATT1  = ws;  ws += 262144;
  float* ATT2  = ws;  ws += 262144;
  unsigned short* DEGB = (unsigned short*)ws; ws += 131072;
  unsigned short* DEGT = (unsigned short*)ws; ws += 131072;
  unsigned short* K1B  = (unsigned short*)ws; ws += 131072;
  unsigned short* K2B  = (unsigned short*)ws; ws += 131072;
  unsigned short* XTP  = K1B;              // aliases K1B+K2B (dead post-pre)
  unsigned short* P1B  = (unsigned short*)ws; ws += 131072;
  unsigned short* P2B  = (unsigned short*)ws; ws += 131072;
  unsigned short* CA1A = (unsigned short*)ws; ws += 16384;
  unsigned short* CA1B = (unsigned short*)ws; ws += 16384;
  unsigned short* CA2A = (unsigned short*)ws; ws += 16384;
  unsigned short* CA2B = (unsigned short*)ws; ws += 16384;
  unsigned short* DWLT = (unsigned short*)ws; ws += 131072;
  unsigned short* WB1  = (unsigned short*)ws; ws += 1179648;
  unsigned short* WB2  = (unsigned short*)ws; ws += 1179648;

  // 1. small weight packs (WB reorder moved into k_mgemm_pre idle blocks)
  k_pack_all<<<1664,256,0,stream>>>(k1_w1,k2_w1,p1_w,p2_w,
      ca1_w1,ca1_w2,ca2_w1,ca2_w2, deg,
      K1B,K2B,P1B,P2B, CA1A,CA1B,CA2A,CA2B, DEGB,DEGT);

  // 2. TMP{1,2} + HID{1,2} + WB{1,2} reorder [z-batched, 1024 blocks all busy]
  k_mgemm_pre<<<dim3(16,16,4),256,0,stream>>>(DEGB,DEGT, K1B,K2B, CA1A,CA2A,
      conv1_w, conv2_w, TMP1,TMP2, HID1,HID2, WB1,WB2);
  // 3. KERN{1,2} + ATT{1,2} + XTP border zero  [z-batched]
  k_kern_att<<<dim3(128,1,4),256,0,stream>>>(TMP1,TMP2, k1_w2,k2_w2,
      CA1B,CA2B, HID1,HID2, KERN1,KERN2, ATT1,ATT2, XTP);

  // 4. da_conv1 depthwise -> DWLT [px][ch] bf16
  k_dwconv<<<512,512,0,stream>>>(xin, KERN1, DWLT);
  // 5. pointwise 1 (+bias+deg*att+lrelu) -> XTP interior
  k_pw<<<dim3(16,16),256,0,stream>>>(P1B, DWLT, p1_b, deg, ATT1, XTP);
  // 6. conv1 3x3 (64x128 tile, BK=64, split-K=18, global_load_lds staging)
  k_mfma_conv<256><<<dim3(8,4,18),256,0,stream>>>(WB1, XTP, PART);
  // 7. fused reduce+lrelu+depthwise (da_conv2) -> DWLT
  k_dwconv_red<<<512,512,0,stream>>>(PART, conv1_b, KERN2, DWLT, NS);
  // 8. pointwise 2 -> XTP interior
  k_pw<<<dim3(16,16),256,0,stream>>>(P2B, DWLT, p2_b, deg, ATT2, XTP);
  // 9. conv2 3x3
  k_mfma_conv<256><<<dim3(8,4,18),256,0,stream>>>(WB2, XTP, PART);
  // 10. final reduce + bias + residual
  k_reduce_final<<<256,256,0,stream>>>(PART, conv2_b, xin, out, NS);
}

// Round 17
// 75.914 us; speedup vs baseline: 1.1388x; 1.0762x over previous
//
#include <hip/hip_runtime.h>
#include <hip/hip_bf16.h>

typedef __attribute__((ext_vector_type(8))) unsigned short ushort8;
typedef __attribute__((ext_vector_type(8))) __bf16 bf16x8;
typedef __attribute__((ext_vector_type(4))) float f32x4;
typedef __attribute__((ext_vector_type(4))) unsigned short ushort4v;

__device__ __forceinline__ float lrelu_f(float v){ return v > 0.f ? v : 0.1f*v; }

__device__ __forceinline__ unsigned short f2bf(float v){
  unsigned u = __float_as_uint(v);
  unsigned r = (u + 0x7fffu + ((u>>16)&1u)) >> 16;
  return (unsigned short)r;
}
__device__ __forceinline__ float bf2f(unsigned short u){
  return __uint_as_float(((unsigned)u)<<16);
}

__device__ __forceinline__ void gload16(const void* g, void* l){
  __builtin_amdgcn_global_load_lds(
    (const __attribute__((address_space(1))) unsigned int*)g,
    (__attribute__((address_space(3))) unsigned int*)l, 16, 0, 0);
}

__device__ __forceinline__ void packq(const float* __restrict__ s,
                                      unsigned short* __restrict__ d, int i){
  const float4 v = ((const float4*)s)[i];
  ushort4v o; o.x=f2bf(v.x); o.y=f2bf(v.y); o.z=f2bf(v.z); o.w=f2bf(v.w);
  *(ushort4v*)(d + (size_t)i*4) = o;
}

// ============ pack: small weights + deg (WB reorder lives in k_mgemm_pre) ====
__global__ __launch_bounds__(256) void k_pack_all(
  const float* __restrict__ k1_w1, const float* __restrict__ k2_w1,
  const float* __restrict__ p1_w,  const float* __restrict__ p2_w,
  const float* __restrict__ ca1_w1,const float* __restrict__ ca1_w2,
  const float* __restrict__ ca2_w1,const float* __restrict__ ca2_w2,
  const float* __restrict__ deg,
  unsigned short* __restrict__ K1B, unsigned short* __restrict__ K2B,
  unsigned short* __restrict__ P1B, unsigned short* __restrict__ P2B,
  unsigned short* __restrict__ CA1A,unsigned short* __restrict__ CA1B,
  unsigned short* __restrict__ CA2A,unsigned short* __restrict__ CA2B,
  unsigned short* __restrict__ DEGB,unsigned short* __restrict__ DEGT){
  int i = blockIdx.x*256 + threadIdx.x;
  if (i < 65536){ packq(k1_w1, K1B, i); return; } i -= 65536;
  if (i < 65536){ packq(k2_w1, K2B, i); return; } i -= 65536;
  if (i < 65536){ packq(p1_w,  P1B, i); return; } i -= 65536;
  if (i < 65536){ packq(p2_w,  P2B, i); return; } i -= 65536;
  if (i < 8192){ packq(ca1_w1, CA1A, i); return; } i -= 8192;
  if (i < 8192){ packq(ca1_w2, CA1B, i); return; } i -= 8192;
  if (i < 8192){ packq(ca2_w1, CA2A, i); return; } i -= 8192;
  if (i < 8192){ packq(ca2_w2, CA2B, i); return; } i -= 8192;
  if (i < 65536){ packq(deg, DEGB, i); return; } i -= 65536;
  if (i < 65536){                      // DEGT: bf16 transpose of deg
    const int j = i*4; const int p = j>>9, c = j&511;
    ushort4v o;
    o.x = f2bf(deg[(size_t)(c+0)*512 + p]);
    o.y = f2bf(deg[(size_t)(c+1)*512 + p]);
    o.z = f2bf(deg[(size_t)(c+2)*512 + p]);
    o.w = f2bf(deg[(size_t)(c+3)*512 + p]);
    *(ushort4v*)(DEGT + (size_t)j) = o;
  }
}

// ==== 32x32 GEMM core: 4 waves = 4 quadrants, BK=64, dbuf single-barrier ====
__device__ __forceinline__ void gemm32(
    const unsigned short* __restrict__ A, const unsigned short* __restrict__ Bt,
    int m0, int n0, int K, int tid,
    unsigned short* lA, unsigned short* lB, f32x4& acc){
  const int wid = tid>>6, lane = tid&63;
  const int half = tid>>7, st_ = tid&127;
  const int srow = st_>>2, skb = st_&3;
  const unsigned short* gS = (half ? Bt + (size_t)(n0+srow)*K
                                   : A  + (size_t)(m0+srow)*K);
  unsigned short* lS = half ? lB : lA;
  const int soff0 = srow*64 + 8*(skb ^ (srow&7));
  const int soff1 = srow*64 + 8*((skb+4) ^ (srow&7));

  const int wr = (wid>>1)*16, wc = (wid&1)*16;
  const int l15 = lane&15, lkb = lane>>4;
  int aoff[2], boff[2];
  #pragma unroll
  for (int h=0;h<2;h++){
    const int Ra = wr + l15;
    aoff[h] = Ra*64 + 8*((lkb+4*h) ^ (Ra&7));
    const int Rb = wc + l15;
    boff[h] = Rb*64 + 8*((lkb+4*h) ^ (Rb&7));
  }

  const int nst = K>>6;
  ushort8 r0 = *(const ushort8*)(gS + skb*8);
  ushort8 r1 = *(const ushort8*)(gS + (skb+4)*8);
  *(ushort8*)(lS + soff0) = r0;
  *(ushort8*)(lS + soff1) = r1;
  if (nst > 1){
    r0 = *(const ushort8*)(gS + 64 + skb*8);
    r1 = *(const ushort8*)(gS + 64 + (skb+4)*8);
  }
  __syncthreads();
  for (int st=0; st<nst; ++st){
    const int cur = (st&1)*2048;
    bf16x8 af[2], bf[2];
    #pragma unroll
    for (int h=0;h<2;h++){
      af[h] = *(const bf16x8*)(lA + cur + aoff[h]);
      bf[h] = *(const bf16x8*)(lB + cur + boff[h]);
    }
    if (st+1 < nst){
      const int nxt = ((st+1)&1)*2048;
      *(ushort8*)(lS + nxt + soff0) = r0;
      *(ushort8*)(lS + nxt + soff1) = r1;
      if (st+2 < nst){
        r0 = *(const ushort8*)(gS + (size_t)(st+2)*64 + skb*8);
        r1 = *(const ushort8*)(gS + (size_t)(st+2)*64 + (skb+4)*8);
      }
    }
    #pragma unroll
    for (int h=0;h<2;h++)
      acc = __builtin_amdgcn_mfma_f32_16x16x32_bf16(af[h], bf[h], acc, 0,0,0);
    __syncthreads();
  }
}

// ==== pre: z=0,1: 32x32 TMP tile + in-register kw2 contraction -> KP partials
//          z=2,3 y<2: HID{1,2}=lrelu(DEGT@ca_w1^T) bf16 [512][64]
//          z=2,3 y>=2: WB{1,2} conv weight reorder
__global__ __launch_bounds__(256) void k_mgemm_pre(
    const unsigned short* __restrict__ DEGB, const unsigned short* __restrict__ DEGT,
    const unsigned short* __restrict__ K1B,  const unsigned short* __restrict__ K2B,
    const unsigned short* __restrict__ CA1A, const unsigned short* __restrict__ CA2A,
    const float* __restrict__ conv1_w, const float* __restrict__ conv2_w,
    const float* __restrict__ kw2a, const float* __restrict__ kw2b,
    float* __restrict__ KP1, float* __restrict__ KP2,
    unsigned short* __restrict__ HID1, unsigned short* __restrict__ HID2,
    unsigned short* __restrict__ WB1, unsigned short* __restrict__ WB2){
  const int z = blockIdx.z;
  const int tid = threadIdx.x;
  if (z >= 2 && blockIdx.y >= 2){
    const float* src      = (z==2) ? conv1_w : conv2_w;
    unsigned short* dst   = (z==2) ? WB1 : WB2;
    const int base = (((blockIdx.y-2)*16 + blockIdx.x)*256) + tid;
    for (int i = base; i < 589824; i += 57344){
      const int o_ = i/1152; const int r4 = (i - o_*1152)*4;
      const int t = r4>>9; const int ci = r4&511;
      const float* s = src + (size_t)o_*4608;
      ushort4v o;
      o.x = f2bf(s[(ci+0)*9 + t]); o.y = f2bf(s[(ci+1)*9 + t]);
      o.z = f2bf(s[(ci+2)*9 + t]); o.w = f2bf(s[(ci+3)*9 + t]);
      *(ushort4v*)(dst + (size_t)o_*4608 + r4) = o;
    }
    return;
  }
  __shared__ unsigned short lA[4096], lB[4096];
  __shared__ float kp[2][32][9];
  const int wid = tid>>6, lane = tid&63;
  const int l15 = lane&15, lkb = lane>>4;

  if (z < 2){
    const int it = blockIdx.x, jc = blockIdx.y;
    const unsigned short* Bt = z ? K2B : K1B;
    const float* kw2 = z ? kw2b : kw2a;
    float* KP        = z ? KP2 : KP1;
    const int m0 = it*32, n0 = jc*32;
    f32x4 acc = {};
    gemm32(DEGB, Bt, m0, n0, 512, tid, lA, lB, acc);

    const int wr = (wid>>1)*16, wc2 = wid&1;   // wave col-half (0/1)
    const int col = n0 + wc2*16 + l15;
    float w[9];
    #pragma unroll
    for (int t=0;t<9;t++) w[t] = kw2[t*512 + col];
    #pragma unroll
    for (int r=0;r<4;r++){
      const float v = lrelu_f(acc[r]);
      const int row = wr + lkb*4 + r;
      #pragma unroll
      for (int t=0;t<9;t++){
        float q = v*w[t];
        q += __shfl_xor(q,1); q += __shfl_xor(q,2);
        q += __shfl_xor(q,4); q += __shfl_xor(q,8);
        if (l15==0) kp[wc2][row][t] = q;
      }
    }
    __syncthreads();
    for (int i = tid; i < 288; i += 256){
      const int row = i/9, t = i - row*9;
      KP[((size_t)jc*512 + m0 + row)*9 + t] = kp[0][row][t] + kp[1][row][t];
    }
  } else {
    const unsigned short* caw = (z==2) ? CA1A : CA2A;   // [64 h][512 c] bf16
    unsigned short* HID = (z==2) ? HID1 : HID2;
    const int m0 = blockIdx.x*32, n0 = blockIdx.y*32;
    f32x4 acc = {};
    gemm32(DEGT, caw, m0, n0, 512, tid, lA, lB, acc);
    const int wr = (wid>>1)*16, wc = (wid&1)*16;
    #pragma unroll
    for (int r=0;r<4;r++){
      const int row = m0 + wr + lkb*4 + r;
      const int col = n0 + wc + l15;
      HID[(size_t)row*64 + col] = f2bf(lrelu_f(acc[r]));
    }
  }
}

// ======= 64x64 MFMA GEMM core (for ATT K=64 GEMM), 4 waves, dbuf ========
__device__ __forceinline__ void gemm64(
    const unsigned short* __restrict__ A, const unsigned short* __restrict__ Bt,
    int m0, int n0, int K, int tid,
    unsigned short* lA, unsigned short* lB, f32x4 acc[2][2]){
  const int wid = tid>>6, lane = tid&63;
  const int srow = tid>>2, skb = tid&3;
  const unsigned short* gA = A  + (size_t)(m0+srow)*K + skb*8;
  const unsigned short* gB = Bt + (size_t)(n0+srow)*K + skb*8;
  const int soff = srow*32 + 8*(skb ^ (srow&3));
  const int wr = (wid>>1)*32, wc = (wid&1)*32;
  const int l15 = lane&15, lkb = lane>>4;
  int aoff[2], boff[2];
  #pragma unroll
  for (int s=0;s<2;s++){
    const int Ra = wr + s*16 + l15;
    aoff[s] = Ra*32 + 8*(lkb ^ (Ra&3));
    const int Rb = wc + s*16 + l15;
    boff[s] = Rb*32 + 8*(lkb ^ (Rb&3));
  }
  const int nst = K>>5;
  ushort8 ra = *(const ushort8*)gA;
  ushort8 rb = *(const ushort8*)gB;
  *(ushort8*)(lA + soff) = ra;
  *(ushort8*)(lB + soff) = rb;
  if (nst > 1){ ra = *(const ushort8*)(gA+32); rb = *(const ushort8*)(gB+32); }
  __syncthreads();
  for (int st=0; st<nst; ++st){
    const int cur = (st&1)*2048;
    bf16x8 af[2], bfr[2];
    #pragma unroll
    for (int s=0;s<2;s++){
      af[s]  = *(const bf16x8*)(lA + cur + aoff[s]);
      bfr[s] = *(const bf16x8*)(lB + cur + boff[s]);
    }
    if (st+1 < nst){
      const int nxt = ((st+1)&1)*2048;
      *(ushort8*)(lA + nxt + soff) = ra;
      *(ushort8*)(lB + nxt + soff) = rb;
      if (st+2 < nst){
        ra = *(const ushort8*)(gA + (size_t)(st+2)*32);
        rb = *(const ushort8*)(gB + (size_t)(st+2)*32);
      }
    }
    #pragma unroll
    for (int mi=0;mi<2;mi++)
      #pragma unroll
      for (int ni=0;ni<2;ni++)
        acc[mi][ni] = __builtin_amdgcn_mfma_f32_16x16x32_bf16(af[mi], bfr[ni], acc[mi][ni], 0,0,0);
    __syncthreads();
  }
}

// ==== fused: ATT GEMMs (blocks 0..127) + dwconv1 (128..639) + border zero ====
__global__ __launch_bounds__(256) void k_att_dw(
    const unsigned short* __restrict__ CA1B, const unsigned short* __restrict__ CA2B,
    const unsigned short* __restrict__ HID1, const unsigned short* __restrict__ HID2,
    float* __restrict__ ATT1, float* __restrict__ ATT2,
    const float* __restrict__ xin, const float* __restrict__ KP1,
    unsigned short* __restrict__ DWLT, unsigned short* __restrict__ XTP){
  __shared__ __align__(16) unsigned char smem[16640];
  const int tid = threadIdx.x;
  int bid = blockIdx.x;
  if (bid < 128){
    unsigned short* lA = (unsigned short*)smem;
    unsigned short* lB = lA + 4096;
    const int b = bid>>6, t6 = bid&63;
    const unsigned short* A   = b ? CA2B : CA1B;      // [512 c][64 h] bf16
    const unsigned short* Bt  = b ? HID2 : HID1;      // [512 px][64 h] bf16
    float* ATT                = b ? ATT2 : ATT1;
    const int m0 = (t6>>3)*64, n0 = (t6&7)*64;
    f32x4 acc[2][2] = {};
    gemm64(A, Bt, m0, n0, 64, tid, lA, lB, acc);
    const int wid = tid>>6, lane = tid&63;
    const int wr = (wid>>1)*32, wc = (wid&1)*32;
    const int l15 = lane&15, lkb = lane>>4;
    #pragma unroll
    for (int mi=0;mi<2;mi++)
      #pragma unroll
      for (int ni=0;ni<2;ni++){
        const int row = m0 + wr + mi*16 + lkb*4;
        const int col = n0 + wc + ni*16 + l15;
        #pragma unroll
        for (int r=0;r<4;r++)
          ATT[(size_t)(row+r)*512 + col] = 1.f/(1.f + expf(-acc[mi][ni][r]));
      }
  } else {
    bid -= 128;
    const int c = bid;
    {  // XTP halo border zero (100 slots x 512 ch = 12800 quads, 50 blocks)
      const int idx = bid*256 + tid;
      if (idx < 12800){
        const int si = idx>>7, wi = idx&127;
        int slot;
        if (si < 34) slot = si;
        else if (si < 68) slot = 578 + (si-34);
        else if (si < 84) slot = (si-67)*34;
        else slot = (si-83)*34 + 33;
        ushort4v zz = {};
        *(ushort4v*)(XTP + (size_t)slot*512 + wi*4) = zz;
      }
    }
    float* plane = (float*)smem;     // 612
    float* ks = plane + 612;         // 9
    for (int i=tid;i<612;i+=256) plane[i]=0.f;
    if (tid<9){
      float s=0.f;
      #pragma unroll
      for (int jc=0;jc<16;jc++) s += KP1[((size_t)jc*512 + c)*9 + tid];
      ks[tid]=s;
    }
    #pragma unroll
    for (int q=0;q<2;q++){
      const int px = tid + q*256;
      plane[((px>>5)+1)*34 + (px&31)+1] = xin[(size_t)c*512 + px];
    }
    __syncthreads();
    #pragma unroll
    for (int q=0;q<2;q++){
      const int px = tid + q*256;
      const int iy = px>>5, ix = px&31;
      float s = 0.f;
      #pragma unroll
      for (int dy=0;dy<3;dy++)
        #pragma unroll
        for (int dx=0;dx<3;dx++)
          s += plane[(iy+dy)*34 + ix+dx]*ks[dy*3+dx];
      DWLT[(size_t)px*512 + c] = f2bf(lrelu_f(s));
    }
  }
}

// ==== fused: reduce 18 bf16 conv partials + bias + lrelu, then dw2 -> yt =====
__global__ __launch_bounds__(512) void k_dwconv_red(const unsigned short* __restrict__ part,
    const float* __restrict__ bias, const float* __restrict__ KP,
    unsigned short* __restrict__ yt, int nchunks){
  const int c = blockIdx.x;
  const int p = threadIdx.x;
  const int iy = p>>5, ix = p&31;
  __shared__ float plane[18*34];
  __shared__ float ks[9];
  for (int i=p;i<18*34;i+=512) plane[i]=0.f;
  if (p < 9){
    float s = 0.f;
    #pragma unroll
    for (int jc=0;jc<16;jc++) s += KP[((size_t)jc*512 + c)*9 + p];
    ks[p] = s;
  }
  __syncthreads();
  if (p < 128){
    const float b = bias[c];
    float4 a4 = {b,b,b,b};
    for (int s=0;s<nchunks;s++){
      const ushort4v v = ((const ushort4v*)(part + (size_t)s*262144 + c*512))[p];
      a4.x += bf2f(v.x); a4.y += bf2f(v.y); a4.z += bf2f(v.z); a4.w += bf2f(v.w);
    }
    a4.x = lrelu_f(a4.x); a4.y = lrelu_f(a4.y);
    a4.z = lrelu_f(a4.z); a4.w = lrelu_f(a4.w);
    const int px0 = p*4;
    float* dst = &plane[((px0>>5)+1)*34 + (px0&31)+1];
    dst[0]=a4.x; dst[1]=a4.y; dst[2]=a4.z; dst[3]=a4.w;
  }
  __syncthreads();
  float s = 0.f;
  #pragma unroll
  for (int dy=0;dy<3;dy++)
    #pragma unroll
    for (int dx=0;dx<3;dx++)
      s += plane[(iy+dy)*34 + ix+dx]*ks[dy*3+dx];
  yt[(size_t)p*512 + c] = f2bf(lrelu_f(s));
}

// ==== pointwise GEMM 32x32-tile, BK=64 (8 steps); OUT -> XTP halo ============
__global__ __launch_bounds__(256) void k_pw(
    const unsigned short* __restrict__ A, const unsigned short* __restrict__ Bt,
    const float* __restrict__ bias,
    const float* __restrict__ E1, const float* __restrict__ E2,
    unsigned short* __restrict__ XTP){
  __shared__ unsigned short lA[4096], lB[4096];
  __shared__ float tile[32][33];
  const int tid = threadIdx.x;
  const int wid = tid>>6, lane = tid&63;
  const int M0 = blockIdx.x*32, N0 = blockIdx.y*32;

  f32x4 acc = {};
  gemm32(A, Bt, M0, N0, 512, tid, lA, lB, acc);

  const int wr = (wid>>1)*16, wc = (wid&1)*16;
  const int l15 = lane&15, lkb = lane>>4;
  #pragma unroll
  for (int r=0;r<4;r++){
    const int rl = wr + lkb*4 + r;
    const int cl = wc + l15;
    const int rr = M0 + rl, col = N0 + cl;
    float v = acc[r] + bias[rr] + E1[(size_t)rr*512+col]*E2[(size_t)rr*512+col];
    tile[rl][cl] = lrelu_f(v);
  }
  __syncthreads();
  const int pr = tid>>3, q = tid&7;
  const int p = N0 + pr;
  const int slot = ((p>>5)+1)*34 + (p&31) + 1;
  ushort4v o;
  o.x = f2bf(tile[q*4+0][pr]); o.y = f2bf(tile[q*4+1][pr]);
  o.z = f2bf(tile[q*4+2][pr]); o.w = f2bf(tile[q*4+3][pr]);
  *(ushort4v*)(XTP + (size_t)slot*512 + M0 + q*4) = o;
}

// ===== conv 3x3 MFMA GEMM 64x128 tile, BK=64, global_load_lds staging ========
template<int KCH>   // 256
__global__ __launch_bounds__(256) void k_mfma_conv(
    const unsigned short* __restrict__ WB,
    const unsigned short* __restrict__ XTP,
    unsigned short* __restrict__ part){
  __shared__ __attribute__((aligned(16))) unsigned short lA[2][4096];
  __shared__ __attribute__((aligned(16))) unsigned short lB[2][8192];
  const int tid = threadIdx.x;
  const int wid = tid>>6, lane = tid&63;
  const int m0 = blockIdx.x*64, n0 = blockIdx.y*128;
  const int k0 = blockIdx.z*KCH;

  const int wrow = wid*8 + (lane>>3);
  const int clin = lane&7;
  const unsigned short* asrc[2];
  #pragma unroll
  for (int j=0;j<2;j++){
    const int r = j*32 + wrow;
    asrc[j] = WB + (size_t)(m0+r)*4608 + k0 + (clin ^ (r&7))*8;
  }
  int bpy[4], bpx[4], bchk[4];
  #pragma unroll
  for (int j=0;j<4;j++){
    const int r = j*32 + wrow;
    const int pp = n0 + r;
    bpy[j] = pp>>5; bpx[j] = pp&31;
    bchk[j] = (clin ^ (r&7))*8;
  }

  const int wr = (wid>>1)*32, wc = (wid&1)*64;
  const int l15 = lane&15, lkb = lane>>4;
  int aoff[2][2], boff[4][2];
  #pragma unroll
  for (int s=0;s<2;s++){
    const int Ra = wr + s*16 + l15;
    #pragma unroll
    for (int h=0;h<2;h++) aoff[s][h] = Ra*64 + 8*((lkb+4*h) ^ (Ra&7));
  }
  #pragma unroll
  for (int u=0;u<4;u++){
    const int Rb = wc + u*16 + l15;
    #pragma unroll
    for (int h=0;h<2;h++) boff[u][h] = Rb*64 + 8*((lkb+4*h) ^ (Rb&7));
  }

  auto stage = [&](int buf, int st){
    #pragma unroll
    for (int j=0;j<2;j++)
      gload16(asrc[j] + st*64, &lA[buf][j*2048 + wid*512]);
    const int k = k0 + st*64;
    const int t = k>>9;
    const int dy = t/3, dx = t - dy*3;
    const int kc = k & 511;
    #pragma unroll
    for (int j=0;j<4;j++){
      const int slot = (bpy[j]+dy)*34 + bpx[j]+dx;
      gload16(XTP + (size_t)slot*512 + kc + bchk[j],
              &lB[buf][j*2048 + wid*512]);
    }
  };

  constexpr int NST = KCH/64;
  f32x4 acc[2][4] = {};
  stage(0, 0);
  __syncthreads();
  #pragma unroll
  for (int st=0; st<NST; ++st){
    const int cur = st&1;
    if (st+1 < NST) stage(cur^1, st+1);
    bf16x8 af[2][2], bfr[4][2];
    #pragma unroll
    for (int s=0;s<2;s++)
      #pragma unroll
      for (int h=0;h<2;h++) af[s][h] = *(const bf16x8*)(&lA[cur][aoff[s][h]]);
    #pragma unroll
    for (int u=0;u<4;u++)
      #pragma unroll
      for (int h=0;h<2;h++) bfr[u][h] = *(const bf16x8*)(&lB[cur][boff[u][h]]);
    #pragma unroll
    for (int h=0;h<2;h++)
      #pragma unroll
      for (int s=0;s<2;s++)
        #pragma unroll
        for (int u=0;u<4;u++)
          acc[s][u] = __builtin_amdgcn_mfma_f32_16x16x32_bf16(af[s][h], bfr[u][h], acc[s][u], 0,0,0);
    __syncthreads();
  }

  unsigned short* pbase = part + (size_t)blockIdx.z*262144;
  #pragma unroll
  for (int s=0;s<2;s++)
    #pragma unroll
    for (int u=0;u<4;u++){
      const int row = m0 + wr + s*16 + lkb*4;
      const int col = n0 + wc + u*16 + l15;
      #pragma unroll
      for (int r=0;r<4;r++)
        pbase[(size_t)(row+r)*512 + col] = f2bf(acc[s][u][r]);
    }
}

// ===== final reduce: bias + bf16 partials + residual =========================
__global__ __launch_bounds__(256) void k_reduce_final(const unsigned short* __restrict__ part,
    const float* __restrict__ bias, const float* __restrict__ res,
    float* __restrict__ y, int nchunks){
  const int i = blockIdx.x*256 + threadIdx.x;
  const int o = i>>7;
  const float b = bias[o];
  float4 a4 = {b,b,b,b};
  for (int s=0;s<nchunks;s++){
    const ushort4v v = ((const ushort4v*)part)[(size_t)s*65536 + i];
    a4.x += bf2f(v.x); a4.y += bf2f(v.y); a4.z += bf2f(v.z); a4.w += bf2f(v.w);
  }
  const float4 rv = ((const float4*)res)[i];
  a4.x += rv.x; a4.y += rv.y; a4.z += rv.z; a4.w += rv.w;
  ((float4*)y)[i] = a4;
}

extern "C" void kernel_launch(void* const* d_in, const int* in_sizes, int n_in,
                              void* d_out, int out_size, void* d_ws, size_t ws_size,
                              hipStream_t stream) {
  (void)in_sizes; (void)n_in; (void)out_size; (void)ws_size;
  const float* xin    = (const float*)d_in[0];
  const float* deg    = (const float*)d_in[1];
  const float* k1_w1  = (const float*)d_in[2];
  const float* k1_w2  = (const float*)d_in[3];
  const float* p1_w   = (const float*)d_in[4];
  const float* p1_b   = (const float*)d_in[5];
  const float* ca1_w1 = (const float*)d_in[6];
  const float* ca1_w2 = (const float*)d_in[7];
  const float* conv1_w= (const float*)d_in[8];
  const float* conv1_b= (const float*)d_in[9];
  const float* k2_w1  = (const float*)d_in[10];
  const float* k2_w2  = (const float*)d_in[11];
  const float* p2_w   = (const float*)d_in[12];
  const float* p2_b   = (const float*)d_in[13];
  const float* ca2_w1 = (const float*)d_in[14];
  const float* ca2_w2 = (const float*)d_in[15];
  const float* conv2_w= (const float*)d_in[16];
  const float* conv2_b= (const float*)d_in[17];
  float* out = (float*)d_out;

  const int NS = 18;                       // conv split-K chunks (KCH=256)

  // ---- workspace ----
  float* ws = (float*)d_ws;
  unsigned short* PART = (unsigned short*)ws;
  ws += (size_t)NS*131072;                 // 9.4 MB
  // HID aliases PART region (consumed at k_att_dw, before conv1 writes PART)
  unsigned short* HID1 = PART;             // 32768 us
  unsigned short* HID2 = HID1 + 32768;
  float* KP1  = ws;  ws += 73728;          // 16 jc x 512 c x 9 t (persist)
  float* KP2  = ws;  ws += 73728;
  float* ATT1 = ws;  ws += 262144;
  float* ATT2 = ws;  ws += 262144;
  unsigned short* DEGB = (unsigned short*)ws; ws += 131072;
  unsigned short* DEGT = (unsigned short*)ws; ws += 131072;
  unsigned short* K1B  = (unsigned short*)ws; ws += 131072;
  unsigned short* K2B  = (unsigned short*)ws; ws += 131072;
  unsigned short* XTP  = K1B;              // aliases K1B+K2B (dead after pre)
  unsigned short* P1B  = (unsigned short*)ws; ws += 131072;
  unsigned short* P2B  = (unsigned short*)ws; ws += 131072;
  unsigned short* CA1A = (unsigned short*)ws; ws += 16384;
  unsigned short* CA1B = (unsigned short*)ws; ws += 16384;
  unsigned short* CA2A = (unsigned short*)ws; ws += 16384;
  unsigned short* CA2B = (unsigned short*)ws; ws += 16384;
  unsigned short* DWLT = (unsigned short*)ws; ws += 131072;
  unsigned short* WB1  = (unsigned short*)ws; ws += 1179648;
  unsigned short* WB2  = (unsigned short*)ws; ws += 1179648;

  // 1. small weight packs
  k_pack_all<<<1664,256,0,stream>>>(k1_w1,k2_w1,p1_w,p2_w,
      ca1_w1,ca1_w2,ca2_w1,ca2_w2, deg,
      K1B,K2B,P1B,P2B, CA1A,CA1B,CA2A,CA2B, DEGB,DEGT);

  // 2. pre: KP partials (z=0,1) + HID (z=2,3,y<2) + WB reorder (idle blocks)
  k_mgemm_pre<<<dim3(16,16,4),256,0,stream>>>(DEGB,DEGT, K1B,K2B, CA1A,CA2A,
      conv1_w, conv2_w, k1_w2, k2_w2, KP1,KP2, HID1,HID2, WB1,WB2);

  // 3. fused ATT GEMMs + dwconv1 (+ XTP border zero)
  k_att_dw<<<640,256,0,stream>>>(CA1B,CA2B, HID1,HID2, ATT1,ATT2,
      xin, KP1, DWLT, XTP);

  // 4. pointwise 1 (+bias+deg*att+lrelu) -> XTP interior
  k_pw<<<dim3(16,16),256,0,stream>>>(P1B, DWLT, p1_b, deg, ATT1, XTP);
  // 5. conv1 3x3 (64x128 tile, BK=64, split-K=18, global_load_lds staging)
  k_mfma_conv<256><<<dim3(8,4,18),256,0,stream>>>(WB1, XTP, PART);
  // 6. fused reduce+lrelu+depthwise (da_conv2) -> DWLT
  k_dwconv_red<<<512,512,0,stream>>>(PART, conv1_b, KP2, DWLT, NS);
  // 7. pointwise 2 -> XTP interior
  k_pw<<<dim3(16,16),256,0,stream>>>(P2B, DWLT, p2_b, deg, ATT2, XTP);
  // 8. conv2 3x3
  k_mfma_conv<256><<<dim3(8,4,18),256,0,stream>>>(WB2, XTP, PART);
  // 9. final reduce + bias + residual
  k_reduce_final<<<256,256,0,stream>>>(PART, conv2_b, xin, out, NS);
}